// Round 5
// baseline (787.055 us; speedup 1.0000x reference)
//
#include <hip/hip_runtime.h>
#include <hip/hip_bf16.h>
#include <math.h>
#include <float.h>

#define BB 16
#define TT 1023
#define CC 2048
#define M_ROWS (BB * TT)   // 16368
#define MP 16384           // padded rows
#define N3 (3 * CC)        // 6144
#define NCH 16             // scan chunks
#define CHL 64             // chunk length

typedef __attribute__((ext_vector_type(8))) short bfrag;   // 8 bf16 (4 VGPRs)
typedef __attribute__((ext_vector_type(4))) float f32x4;   // MFMA C/D frag
typedef __attribute__((ext_vector_type(4))) short short4v;

__device__ __forceinline__ void async16(const void* g, void* l) {
  __builtin_amdgcn_global_load_lds((const __attribute__((address_space(1))) void*)g,
                                   (__attribute__((address_space(3))) void*)l, 16, 0, 0);
}

__device__ __forceinline__ short bfb(float f) {
  __hip_bfloat16 h = __float2bfloat16(f);
  return *reinterpret_cast<short*>(&h);
}

// ---------------- weight fp32 -> bf16 (float4 vectorized) ----------------
__global__ void cast_weights(const float* __restrict__ Wk, const float* __restrict__ Wv,
                             const float* __restrict__ Wr, const float* __restrict__ Wo,
                             __hip_bfloat16* __restrict__ W3, __hip_bfloat16* __restrict__ WoB) {
  size_t i4 = (size_t)blockIdx.x * 256 + threadIdx.x;      // grid covers CC*CC/4
  size_t i = i4 * 4;
  float4 a = *(const float4*)(Wk + i);
  float4 b = *(const float4*)(Wv + i);
  float4 c = *(const float4*)(Wr + i);
  float4 d = *(const float4*)(Wo + i);
  *(short4v*)((short*)W3 + i)              = short4v{bfb(a.x), bfb(a.y), bfb(a.z), bfb(a.w)};
  *(short4v*)((short*)W3 + i + CC * CC)    = short4v{bfb(b.x), bfb(b.y), bfb(b.z), bfb(b.w)};
  *(short4v*)((short*)W3 + i + 2 * CC * CC) = short4v{bfb(c.x), bfb(c.y), bfb(c.z), bfb(c.w)};
  *(short4v*)((short*)WoB + i)             = short4v{bfb(d.x), bfb(d.y), bfb(d.z), bfb(d.w)};
}

// ---------------- xm = x*tm + shift(x)*(1-tm), bf16, padded to MP rows ----------------
__global__ void build_xm(const float* __restrict__ x, const float* __restrict__ xx,
                         const float* __restrict__ tmix, __hip_bfloat16* __restrict__ xm) {
  int m = blockIdx.x;
  short* orow = (short*)xm + (size_t)m * CC;
  if (m >= M_ROWS) {
    for (int c = threadIdx.x; c < CC / 4; c += 256)
      ((short4v*)orow)[c] = short4v{0, 0, 0, 0};
    return;
  }
  int b = m / TT, t = m - b * TT;
  const float* xrow = x + (size_t)m * CC;
  const float* xprev = (t == 0) ? (xx + (size_t)b * CC) : (xrow - CC);
  for (int c = threadIdx.x; c < CC / 4; c += 256) {
    float4 xv = ((const float4*)xrow)[c];
    float4 pv = ((const float4*)xprev)[c];
    float4 tm = ((const float4*)tmix)[c];
    ((short4v*)orow)[c] = short4v{
        bfb(xv.x * tm.x + pv.x * (1.0f - tm.x)),
        bfb(xv.y * tm.y + pv.y * (1.0f - tm.y)),
        bfb(xv.z * tm.z + pv.z * (1.0f - tm.z)),
        bfb(xv.w * tm.w + pv.w * (1.0f - tm.w))};
  }
}

// ---------------- 256x256-tile 2-phase/K-tile bf16 MFMA GEMM ----------------
// C[m,n] = sum_k A[m,k]*B[n,k].  8 waves (2M x 4N), BK=64.
// LDS: 2 buf x 2 khalf x {A,B} regions of 256x32 bf16 (16 KB each) = 128 KB.
// Swizzle: 16B chunk at (row, slot) holds kgrp = slot ^ ((row>>1)&3).
// Per K-tile: PhA = {read B(kh0,kh1)+A(mh0), stage ALL of tile t+1, 32 MFMA};
//             PhB = {read A(mh1), 32 MFMA, VM(0) drain, barrier}.
// Drain slack ~1.5 phases >> HBM latency; no read of a region precedes its drain.
template <int MODE>
__global__ __launch_bounds__(512, 2)
void gemm256(const short* __restrict__ A, const short* __restrict__ Bw,
             float* __restrict__ outF, __hip_bfloat16* __restrict__ outV,
             __hip_bfloat16* __restrict__ outR) {
  __shared__ short lds[65536];   // 128 KiB

  const int lane = threadIdx.x & 63, wid = threadIdx.x >> 6;
  const int wr = wid >> 2, wc = wid & 3;

  // XCD-aware swizzle (grids are multiples of 8)
  const int nx = gridDim.x;
  const int nwg = nx * gridDim.y;
  const int bid = blockIdx.y * nx + blockIdx.x;
  const int q = nwg >> 3;
  const int swz = (bid & 7) * q + (bid >> 3);
  const int mBase = (swz / nx) * 256;
  const int nBase = (swz % nx) * 256;

  // staging: wave wid covers rows [wid*32, wid*32+32) of the 256-row region
  const int srow = lane >> 2;                                  // 0..15
  const int scol = (((lane & 3) ^ ((lane >> 3) & 3)) * 8);     // inverse-swizzled k-group
  const int stgOff = wid * 1024 + lane * 8;                    // shorts
  const short* aSrcBase = A  + (size_t)(mBase + wid * 32 + srow) * CC + scol;
  const short* bSrcBase = Bw + (size_t)(nBase + wid * 32 + srow) * CC + scol;

  // ds_read: frag lane -> (row = R0 + (l&15), kgrp = l>>4), swizzled slot
  const int ldOff = (lane & 15) * 32 + (((lane >> 4) ^ ((lane >> 1) & 3)) * 8);  // shorts

  f32x4 acc[2][4][4] = {};
  bfrag bq[2][4];

#define RGNA(buf, kh) ((buf) * 32768 + (kh) * 8192)
#define RGNB(buf, kh) (16384 + (buf) * 32768 + (kh) * 8192)

#define STG_A(buf, kh, tk) do { \
    const short* _s = aSrcBase + ((tk) * 64 + (kh) * 32); \
    short* _d = lds + RGNA(buf, kh) + stgOff; \
    async16(_s, _d); async16(_s + (size_t)16 * CC, _d + 512); } while (0)

#define STG_B(buf, kh, tk) do { \
    const short* _s = bSrcBase + ((tk) * 64 + (kh) * 32); \
    short* _d = lds + RGNB(buf, kh) + stgOff; \
    async16(_s, _d); async16(_s + (size_t)16 * CC, _d + 512); } while (0)

#define STG4(buf, tk) do { \
    STG_A(buf, 0, tk); STG_B(buf, 0, tk); \
    STG_A(buf, 1, tk); STG_B(buf, 1, tk); } while (0)

#define VM0 asm volatile("s_waitcnt vmcnt(0)" ::: "memory")

  // PhA: read B both kh + A(mh=0) both kh; stage tile t+1; 32 MFMA into acc[0]
#define PHA(buf, STAGE) do { \
    bfrag aq[2][4]; \
    _Pragma("unroll") \
    for (int kh = 0; kh < 2; ++kh) { \
      _Pragma("unroll") \
      for (int n = 0; n < 4; ++n) \
        bq[kh][n] = *(const bfrag*)(lds + RGNB(buf, kh) + (wc * 64 + n * 16) * 32 + ldOff); \
      _Pragma("unroll") \
      for (int f = 0; f < 4; ++f) \
        aq[kh][f] = *(const bfrag*)(lds + RGNA(buf, kh) + (wr * 128 + f * 16) * 32 + ldOff); \
    } \
    STAGE; \
    __builtin_amdgcn_s_barrier(); \
    __builtin_amdgcn_s_setprio(1); \
    _Pragma("unroll") \
    for (int kh = 0; kh < 2; ++kh) \
      _Pragma("unroll") \
      for (int f = 0; f < 4; ++f) \
        _Pragma("unroll") \
        for (int n = 0; n < 4; ++n) \
          acc[0][f][n] = __builtin_amdgcn_mfma_f32_16x16x32_bf16(aq[kh][f], bq[kh][n], acc[0][f][n], 0, 0, 0); \
    __builtin_amdgcn_s_setprio(0); \
    __builtin_amdgcn_s_barrier(); } while (0)

  // PhB: read A(mh=1) both kh; 32 MFMA into acc[1]; WAIT; barrier
#define PHB(buf, WAIT) do { \
    bfrag aq[2][4]; \
    _Pragma("unroll") \
    for (int kh = 0; kh < 2; ++kh) \
      _Pragma("unroll") \
      for (int f = 0; f < 4; ++f) \
        aq[kh][f] = *(const bfrag*)(lds + RGNA(buf, kh) + (wr * 128 + 64 + f * 16) * 32 + ldOff); \
    __builtin_amdgcn_s_barrier(); \
    __builtin_amdgcn_s_setprio(1); \
    _Pragma("unroll") \
    for (int kh = 0; kh < 2; ++kh) \
      _Pragma("unroll") \
      for (int f = 0; f < 4; ++f) \
        _Pragma("unroll") \
        for (int n = 0; n < 4; ++n) \
          acc[1][f][n] = __builtin_amdgcn_mfma_f32_16x16x32_bf16(aq[kh][f], bq[kh][n], acc[1][f][n], 0, 0, 0); \
    __builtin_amdgcn_s_setprio(0); \
    WAIT; \
    __builtin_amdgcn_s_barrier(); } while (0)

  // prologue: stage tile0 -> buf0, drain
  STG4(0, 0);
  VM0;
  __builtin_amdgcn_s_barrier();

  // main loop over K-tile pairs; PhA(t) stages tile t+1 into the other buf
  for (int ti = 0; ti < 30; ti += 2) {
    PHA(0, STG4(1, ti + 1));
    PHB(0, VM0);
    PHA(1, STG4(0, ti + 2));
    PHB(1, VM0);
  }
  PHA(0, STG4(1, 31));
  PHB(0, VM0);
  PHA(1, );
  PHB(1, );

#undef PHA
#undef PHB
#undef VM0
#undef STG4
#undef STG_A
#undef STG_B
#undef RGNA
#undef RGNB

  // C-write: col = lane&15, row = (lane>>4)*4 + rr (verified layout)
#pragma unroll
  for (int mh = 0; mh < 2; ++mh)
#pragma unroll
    for (int f = 0; f < 4; ++f) {
      const int row0 = mBase + wr * 128 + mh * 64 + f * 16 + (lane >> 4) * 4;
      const int col0 = nBase + wc * 64 + (lane & 15);
#pragma unroll
      for (int n = 0; n < 4; ++n) {
        const int col = col0 + n * 16;
#pragma unroll
        for (int rr = 0; rr < 4; ++rr) {
          const int row = row0 + rr;
          if (row < M_ROWS) {
            float val = acc[mh][f][n][rr];
            if constexpr (MODE == 0) {
              outF[(size_t)row * CC + col] = val;
            } else {
              if (col < CC)          outF[(size_t)row * CC + col] = val;
              else if (col < 2 * CC) outV[(size_t)row * CC + (col - CC)] = __float2bfloat16(val);
              else                   outR[(size_t)row * CC + (col - 2 * CC)] = __float2bfloat16(val);
            }
          }
        }
      }
    }
}

// ---------------- chunked parallel scan + sigmoid(r)*wkv/wk ----------------
// Renorm (mm_new) removed: wkv/wk is exactly invariant to it; state init is
// bb*exp(mm), aa*exp(mm). exp(kraw) is safely bounded in fp32 for this data.
__global__ __launch_bounds__(1024)
void scan_fuse2(const float* __restrict__ kraw, const __hip_bfloat16* __restrict__ v,
                const __hip_bfloat16* __restrict__ r, const float* __restrict__ aa,
                const float* __restrict__ bb, const float* __restrict__ mm,
                const float* __restrict__ tdec, const float* __restrict__ tfir,
                __hip_bfloat16* __restrict__ rwkv) {
  __shared__ float sBk[NCH][64], sBkv[NCH][64], sSk[NCH][64], sSkv[NCH][64];

  const int lane = threadIdx.x & 63, wid = threadIdx.x >> 6;
  const int c = blockIdx.x * 64 + lane;
  const int b = blockIdx.y;
  const int i = b * CC + c;

  const float dexp = expf(tdec[c]);
  const float d    = expf(-dexp);
  const float ef   = expf(tfir[c]);

  const int t0 = wid * CHL;
  const int t1 = (t0 + CHL < TT) ? t0 + CHL : TT;
  const size_t base = (size_t)b * TT * CC + c;

  if (wid < NCH - 1) {
    float Bk = 0.0f, Bkv = 0.0f;
    size_t off = base + (size_t)t0 * CC;
#pragma unroll 4
    for (int t = t0; t < t1; ++t, off += CC) {
      float kk = expf(kraw[off]);
      float kv = kk * __bfloat162float(v[off]);
      Bk = d * Bk + kk;
      Bkv = d * Bkv + kv;
    }
    sBk[wid][lane] = Bk;
    sBkv[wid][lane] = Bkv;
  }
  __syncthreads();

  if (wid == 0) {
    const float d64 = expf(-dexp * (float)CHL);
    const float sc = expf(mm[i]);
    float S = bb[i] * sc, Sv = aa[i] * sc;
#pragma unroll
    for (int j = 0; j < NCH; ++j) {
      sSk[j][lane] = S;
      sSkv[j][lane] = Sv;
      if (j < NCH - 1) {
        S = d64 * S + sBk[j][lane];
        Sv = d64 * Sv + sBkv[j][lane];
      }
    }
  }
  __syncthreads();

  float S = sSk[wid][lane], Sv = sSkv[wid][lane];
  size_t off = base + (size_t)t0 * CC;
#pragma unroll 4
  for (int t = t0; t < t1; ++t, off += CC) {
    float kk = expf(kraw[off]);
    float vv = __bfloat162float(v[off]);
    float rv = __bfloat162float(r[off]);
    float kv = kk * vv;
    float wk = ef * kk + S;
    float wkv = ef * kv + Sv;
    S = d * S + kk;
    Sv = d * Sv + kv;
    float ratio = wkv / wk;
    if (isnan(ratio)) ratio = 0.0f;
    else if (isinf(ratio)) ratio = ratio > 0.0f ? FLT_MAX : -FLT_MAX;
    float sig = 1.0f / (1.0f + expf(-rv));
    rwkv[off] = __float2bfloat16(sig * ratio);
  }
}

extern "C" void kernel_launch(void* const* d_in, const int* in_sizes, int n_in,
                              void* d_out, int out_size, void* d_ws, size_t ws_size,
                              hipStream_t stream) {
  const float* x    = (const float*)d_in[0];
  const float* tdec = (const float*)d_in[1];
  const float* tfir = (const float*)d_in[2];
  const float* tmix = (const float*)d_in[3];
  const float* Wk   = (const float*)d_in[4];
  const float* Wv   = (const float*)d_in[5];
  const float* Wr   = (const float*)d_in[6];
  const float* Wo   = (const float*)d_in[7];
  const float* xx   = (const float*)d_in[8];
  const float* aa   = (const float*)d_in[9];
  const float* bb   = (const float*)d_in[10];
  const float* mm   = (const float*)d_in[11];

  char* ws = (char*)d_ws;
  size_t o = 0;
  __hip_bfloat16* W3  = (__hip_bfloat16*)(ws + o); o += (size_t)N3 * CC * 2;
  __hip_bfloat16* WoB = (__hip_bfloat16*)(ws + o); o += (size_t)CC * CC * 2;
  __hip_bfloat16* xmB = (__hip_bfloat16*)(ws + o); o += (size_t)MP * CC * 2;
  __hip_bfloat16* vB  = (__hip_bfloat16*)(ws + o); o += (size_t)MP * CC * 2;
  __hip_bfloat16* rB  = (__hip_bfloat16*)(ws + o); o += (size_t)MP * CC * 2;

  float* kraw = (float*)d_out;
  __hip_bfloat16* rwkvB = xmB;

  cast_weights<<<CC * CC / 1024, 256, 0, stream>>>(Wk, Wv, Wr, Wo, W3, WoB);
  build_xm<<<MP, 256, 0, stream>>>(x, xx, tmix, xmB);
  gemm256<1><<<dim3(N3 / 256, MP / 256), 512, 0, stream>>>(
      (const short*)xmB, (const short*)W3, kraw, vB, rB);
  scan_fuse2<<<dim3(CC / 64, BB), 1024, 0, stream>>>(kraw, vB, rB, aa, bb, mm,
                                                     tdec, tfir, rwkvB);
  gemm256<0><<<dim3(CC / 256, MP / 256), 512, 0, stream>>>(
      (const short*)rwkvB, (const short*)WoB, (float*)d_out, nullptr, nullptr);
}

// Round 6
// 767.584 us; speedup vs baseline: 1.0254x; 1.0254x over previous
//
#include <hip/hip_runtime.h>
#include <hip/hip_bf16.h>
#include <math.h>
#include <float.h>

#define BB 16
#define TT 1023
#define CC 2048
#define M_ROWS (BB * TT)   // 16368
#define MP 16384           // padded rows
#define N3 (3 * CC)        // 6144
#define NCH 16             // scan chunks
#define CHL 64             // chunk length

typedef __attribute__((ext_vector_type(8))) short bfrag;   // 8 bf16 (4 VGPRs)
typedef __attribute__((ext_vector_type(4))) float f32x4;   // MFMA C/D frag
typedef __attribute__((ext_vector_type(4))) short short4v;

__device__ __forceinline__ void async16(const void* g, void* l) {
  __builtin_amdgcn_global_load_lds((const __attribute__((address_space(1))) void*)g,
                                   (__attribute__((address_space(3))) void*)l, 16, 0, 0);
}

__device__ __forceinline__ short bfb(float f) {
  __hip_bfloat16 h = __float2bfloat16(f);
  return *reinterpret_cast<short*>(&h);
}

__device__ __forceinline__ float b2f(unsigned short u) {
  return __uint_as_float((unsigned int)u << 16);
}

// ---------------- weight fp32 -> bf16 (float4 vectorized) ----------------
__global__ void cast_weights(const float* __restrict__ Wk, const float* __restrict__ Wv,
                             const float* __restrict__ Wr, const float* __restrict__ Wo,
                             __hip_bfloat16* __restrict__ W3, __hip_bfloat16* __restrict__ WoB) {
  size_t i4 = (size_t)blockIdx.x * 256 + threadIdx.x;      // grid covers CC*CC/4
  size_t i = i4 * 4;
  float4 a = *(const float4*)(Wk + i);
  float4 b = *(const float4*)(Wv + i);
  float4 c = *(const float4*)(Wr + i);
  float4 d = *(const float4*)(Wo + i);
  *(short4v*)((short*)W3 + i)              = short4v{bfb(a.x), bfb(a.y), bfb(a.z), bfb(a.w)};
  *(short4v*)((short*)W3 + i + CC * CC)    = short4v{bfb(b.x), bfb(b.y), bfb(b.z), bfb(b.w)};
  *(short4v*)((short*)W3 + i + 2 * CC * CC) = short4v{bfb(c.x), bfb(c.y), bfb(c.z), bfb(c.w)};
  *(short4v*)((short*)WoB + i)             = short4v{bfb(d.x), bfb(d.y), bfb(d.z), bfb(d.w)};
}

// ---------------- xm = x*tm + shift(x)*(1-tm), bf16, padded to MP rows ----------------
__global__ void build_xm(const float* __restrict__ x, const float* __restrict__ xx,
                         const float* __restrict__ tmix, __hip_bfloat16* __restrict__ xm) {
  int m = blockIdx.x;
  short* orow = (short*)xm + (size_t)m * CC;
  if (m >= M_ROWS) {
    for (int c = threadIdx.x; c < CC / 4; c += 256)
      ((short4v*)orow)[c] = short4v{0, 0, 0, 0};
    return;
  }
  int b = m / TT, t = m - b * TT;
  const float* xrow = x + (size_t)m * CC;
  const float* xprev = (t == 0) ? (xx + (size_t)b * CC) : (xrow - CC);
  for (int c = threadIdx.x; c < CC / 4; c += 256) {
    float4 xv = ((const float4*)xrow)[c];
    float4 pv = ((const float4*)xprev)[c];
    float4 tm = ((const float4*)tmix)[c];
    ((short4v*)orow)[c] = short4v{
        bfb(xv.x * tm.x + pv.x * (1.0f - tm.x)),
        bfb(xv.y * tm.y + pv.y * (1.0f - tm.y)),
        bfb(xv.z * tm.z + pv.z * (1.0f - tm.z)),
        bfb(xv.w * tm.w + pv.w * (1.0f - tm.w))};
  }
}

// ---------------- 256x256-tile free-run bf16 MFMA GEMM ----------------
// C[m,n] = sum_k A[m,k]*B[n,k].  8 waves (2M x 4N), BK=64.
// LDS: 2 buf x 2 khalf x {A,B} regions of 256x32 bf16 (16 KB each) = 128 KB.
// Swizzle: 16B chunk at (row, slot) holds kgrp = slot ^ ((row>>1)&3)  (verified r3-r5).
// Per K-tile: stage ALL of tile t+1 at tile start (lead ~= 1 K-tile >> HBM lat),
// then 4 sub-phases {ds_read, 16 MFMA} with NO barriers (waves free-run; no LDS
// region is written intra-tile), then VM0 + ONE barrier.  Safety: stages target
// the buffer whose readers all passed the previous boundary barrier; reads of a
// buffer follow the VM0+barrier that drains its stages.
template <int MODE>
__global__ __launch_bounds__(512, 2)
void gemm256(const short* __restrict__ A, const short* __restrict__ Bw,
             float* __restrict__ outF, __hip_bfloat16* __restrict__ outV,
             __hip_bfloat16* __restrict__ outR) {
  __shared__ short lds[65536];   // 128 KiB

  const int lane = threadIdx.x & 63, wid = threadIdx.x >> 6;
  const int wr = wid >> 2, wc = wid & 3;

  // XCD-aware swizzle (grids are multiples of 8)
  const int nx = gridDim.x;
  const int nwg = nx * gridDim.y;
  const int bid = blockIdx.y * nx + blockIdx.x;
  const int q = nwg >> 3;
  const int swz = (bid & 7) * q + (bid >> 3);
  const int mBase = (swz / nx) * 256;
  const int nBase = (swz % nx) * 256;

  // staging: wave wid covers rows [wid*32, wid*32+32) of the 256-row region
  const int srow = lane >> 2;                                  // 0..15
  const int scol = (((lane & 3) ^ ((lane >> 3) & 3)) * 8);     // inverse-swizzled k-group
  const int stgOff = wid * 1024 + lane * 8;                    // shorts
  const short* aSrcBase = A  + (size_t)(mBase + wid * 32 + srow) * CC + scol;
  const short* bSrcBase = Bw + (size_t)(nBase + wid * 32 + srow) * CC + scol;

  // ds_read: frag lane -> (row = R0 + (l&15), kgrp = l>>4), swizzled slot
  const int ldOff = (lane & 15) * 32 + (((lane >> 4) ^ ((lane >> 1) & 3)) * 8);  // shorts

  f32x4 acc[2][4][4] = {};

#define RGNA(buf, kh) ((buf) * 32768 + (kh) * 8192)
#define RGNB(buf, kh) (16384 + (buf) * 32768 + (kh) * 8192)

#define STG_A(buf, kh, tk) do { \
    const short* _s = aSrcBase + ((tk) * 64 + (kh) * 32); \
    short* _d = lds + RGNA(buf, kh) + stgOff; \
    async16(_s, _d); async16(_s + (size_t)16 * CC, _d + 512); } while (0)

#define STG_B(buf, kh, tk) do { \
    const short* _s = bSrcBase + ((tk) * 64 + (kh) * 32); \
    short* _d = lds + RGNB(buf, kh) + stgOff; \
    async16(_s, _d); async16(_s + (size_t)16 * CC, _d + 512); } while (0)

#define STG4(buf, tk) do { \
    STG_A(buf, 0, tk); STG_B(buf, 0, tk); \
    STG_A(buf, 1, tk); STG_B(buf, 1, tk); } while (0)

#define VM0 asm volatile("s_waitcnt vmcnt(0)" ::: "memory")

#define LDB(dst, buf, kh) \
    _Pragma("unroll") \
    for (int n = 0; n < 4; ++n) \
      dst[n] = *(const bfrag*)(lds + RGNB(buf, kh) + (wc * 64 + n * 16) * 32 + ldOff);

#define LDA(dst, buf, kh, mh) \
    _Pragma("unroll") \
    for (int f = 0; f < 4; ++f) \
      dst[f] = *(const bfrag*)(lds + RGNA(buf, kh) + (wr * 128 + (mh) * 64 + f * 16) * 32 + ldOff);

#define MM(ai, bi, m) \
    __builtin_amdgcn_s_setprio(1); \
    _Pragma("unroll") \
    for (int f = 0; f < 4; ++f) \
      _Pragma("unroll") \
      for (int n = 0; n < 4; ++n) \
        acc[m][f][n] = __builtin_amdgcn_mfma_f32_16x16x32_bf16(ai[f], bi[n], acc[m][f][n], 0, 0, 0); \
    __builtin_amdgcn_s_setprio(0);

  // TILE: read buf, stage next tile at start, one VM0+barrier at end
#define TILE(buf, STAGE) do { \
    bfrag a0[4], a1[4], b0[4], b1[4]; \
    LDB(b0, buf, 0) LDA(a0, buf, 0, 0) \
    STAGE; \
    MM(a0, b0, 0) \
    LDA(a1, buf, 0, 1) \
    MM(a1, b0, 1) \
    LDB(b1, buf, 1) LDA(a0, buf, 1, 0) \
    MM(a0, b1, 0) \
    LDA(a1, buf, 1, 1) \
    MM(a1, b1, 1) \
    VM0; \
    __builtin_amdgcn_s_barrier(); } while (0)

  // prologue: stage tile0 -> buf0, drain
  STG4(0, 0);
  VM0;
  __builtin_amdgcn_s_barrier();

  for (int ti = 0; ti < 30; ti += 2) {
    TILE(0, STG4(1, ti + 1));
    TILE(1, STG4(0, ti + 2));
  }
  TILE(0, STG4(1, 31));
  { // final tile: no stage, no VM/barrier needed before C-write
    bfrag a0[4], a1[4], b0[4], b1[4];
    LDB(b0, 1, 0) LDA(a0, 1, 0, 0)
    MM(a0, b0, 0)
    LDA(a1, 1, 0, 1)
    MM(a1, b0, 1)
    LDB(b1, 1, 1) LDA(a0, 1, 1, 0)
    MM(a0, b1, 0)
    LDA(a1, 1, 1, 1)
    MM(a1, b1, 1)
  }

#undef TILE
#undef MM
#undef LDA
#undef LDB
#undef VM0
#undef STG4
#undef STG_A
#undef STG_B
#undef RGNA
#undef RGNB

  // C-write: col = lane&15, row = (lane>>4)*4 + rr (verified layout)
#pragma unroll
  for (int mh = 0; mh < 2; ++mh)
#pragma unroll
    for (int f = 0; f < 4; ++f) {
      const int row0 = mBase + wr * 128 + mh * 64 + f * 16 + (lane >> 4) * 4;
      const int col0 = nBase + wc * 64 + (lane & 15);
#pragma unroll
      for (int n = 0; n < 4; ++n) {
        const int col = col0 + n * 16;
#pragma unroll
        for (int rr = 0; rr < 4; ++rr) {
          const int row = row0 + rr;
          if (row < M_ROWS) {
            float val = acc[mh][f][n][rr];
            if constexpr (MODE == 0) {
              outF[(size_t)row * CC + col] = val;
            } else {
              if (col < CC)          outF[(size_t)row * CC + col] = val;
              else if (col < 2 * CC) outV[(size_t)row * CC + (col - CC)] = __float2bfloat16(val);
              else                   outR[(size_t)row * CC + (col - 2 * CC)] = __float2bfloat16(val);
            }
          }
        }
      }
    }
}

// ---------------- chunked parallel scan + sigmoid(r)*wkv/wk, 2 ch/lane ----------------
// Renorm removed (ratio invariant); state init bb*exp(mm), aa*exp(mm).
__global__ __launch_bounds__(1024)
void scan_fuse2(const float* __restrict__ kraw, const __hip_bfloat16* __restrict__ v,
                const __hip_bfloat16* __restrict__ r, const float* __restrict__ aa,
                const float* __restrict__ bb, const float* __restrict__ mm,
                const float* __restrict__ tdec, const float* __restrict__ tfir,
                __hip_bfloat16* __restrict__ rwkv) {
  __shared__ float2 sBk[NCH][64], sBkv[NCH][64], sSk[NCH][64], sSkv[NCH][64];  // 32 KB

  const int lane = threadIdx.x & 63, wid = threadIdx.x >> 6;
  const int c = blockIdx.x * 128 + lane * 2;   // two channels: c, c+1
  const int b = blockIdx.y;
  const int i = b * CC + c;

  float2 de, d, ef;
  de.x = expf(tdec[c]);     de.y = expf(tdec[c + 1]);
  d.x  = expf(-de.x);       d.y  = expf(-de.y);
  ef.x = expf(tfir[c]);     ef.y = expf(tfir[c + 1]);

  const int t0 = wid * CHL;
  const int t1 = (t0 + CHL < TT) ? t0 + CHL : TT;
  const size_t base = (size_t)b * TT * CC + c;

  if (wid < NCH - 1) {
    float2 Bk = {0.0f, 0.0f}, Bkv = {0.0f, 0.0f};
    size_t off = base + (size_t)t0 * CC;
#pragma unroll 4
    for (int t = t0; t < t1; ++t, off += CC) {
      float2 k2 = *(const float2*)(kraw + off);
      ushort2 v2 = *(const ushort2*)((const unsigned short*)v + off);
      float kk0 = expf(k2.x), kk1 = expf(k2.y);
      Bk.x = d.x * Bk.x + kk0;           Bk.y = d.y * Bk.y + kk1;
      Bkv.x = d.x * Bkv.x + kk0 * b2f(v2.x);
      Bkv.y = d.y * Bkv.y + kk1 * b2f(v2.y);
    }
    sBk[wid][lane] = Bk;
    sBkv[wid][lane] = Bkv;
  }
  __syncthreads();

  if (wid == 0) {
    float2 d64, S, Sv;
    d64.x = expf(-de.x * (float)CHL);  d64.y = expf(-de.y * (float)CHL);
    float sc0 = expf(mm[i]), sc1 = expf(mm[i + 1]);
    S.x = bb[i] * sc0;      S.y = bb[i + 1] * sc1;
    Sv.x = aa[i] * sc0;     Sv.y = aa[i + 1] * sc1;
#pragma unroll
    for (int j = 0; j < NCH; ++j) {
      sSk[j][lane] = S;
      sSkv[j][lane] = Sv;
      if (j < NCH - 1) {
        float2 Bk = sBk[j][lane], Bkv = sBkv[j][lane];
        S.x = d64.x * S.x + Bk.x;    S.y = d64.y * S.y + Bk.y;
        Sv.x = d64.x * Sv.x + Bkv.x; Sv.y = d64.y * Sv.y + Bkv.y;
      }
    }
  }
  __syncthreads();

  float2 S = sSk[wid][lane], Sv = sSkv[wid][lane];
  size_t off = base + (size_t)t0 * CC;
#pragma unroll 4
  for (int t = t0; t < t1; ++t, off += CC) {
    float2 k2 = *(const float2*)(kraw + off);
    ushort2 v2 = *(const ushort2*)((const unsigned short*)v + off);
    ushort2 r2 = *(const ushort2*)((const unsigned short*)r + off);
    float kk0 = expf(k2.x), kk1 = expf(k2.y);
    float kv0 = kk0 * b2f(v2.x), kv1 = kk1 * b2f(v2.y);
    float wk0 = ef.x * kk0 + S.x,   wk1 = ef.y * kk1 + S.y;
    float wkv0 = ef.x * kv0 + Sv.x, wkv1 = ef.y * kv1 + Sv.y;
    S.x = d.x * S.x + kk0;   S.y = d.y * S.y + kk1;
    Sv.x = d.x * Sv.x + kv0; Sv.y = d.y * Sv.y + kv1;
    float ra0 = wkv0 / wk0, ra1 = wkv1 / wk1;
    if (isnan(ra0)) ra0 = 0.0f;
    else if (isinf(ra0)) ra0 = ra0 > 0.0f ? FLT_MAX : -FLT_MAX;
    if (isnan(ra1)) ra1 = 0.0f;
    else if (isinf(ra1)) ra1 = ra1 > 0.0f ? FLT_MAX : -FLT_MAX;
    float s0 = 1.0f / (1.0f + expf(-b2f(r2.x)));
    float s1 = 1.0f / (1.0f + expf(-b2f(r2.y)));
    ushort2 o;
    o.x = (unsigned short)bfb(s0 * ra0);
    o.y = (unsigned short)bfb(s1 * ra1);
    *(ushort2*)((unsigned short*)rwkv + off) = o;
  }
}

extern "C" void kernel_launch(void* const* d_in, const int* in_sizes, int n_in,
                              void* d_out, int out_size, void* d_ws, size_t ws_size,
                              hipStream_t stream) {
  const float* x    = (const float*)d_in[0];
  const float* tdec = (const float*)d_in[1];
  const float* tfir = (const float*)d_in[2];
  const float* tmix = (const float*)d_in[3];
  const float* Wk   = (const float*)d_in[4];
  const float* Wv   = (const float*)d_in[5];
  const float* Wr   = (const float*)d_in[6];
  const float* Wo   = (const float*)d_in[7];
  const float* xx   = (const float*)d_in[8];
  const float* aa   = (const float*)d_in[9];
  const float* bb   = (const float*)d_in[10];
  const float* mm   = (const float*)d_in[11];

  char* ws = (char*)d_ws;
  size_t o = 0;
  __hip_bfloat16* W3  = (__hip_bfloat16*)(ws + o); o += (size_t)N3 * CC * 2;
  __hip_bfloat16* WoB = (__hip_bfloat16*)(ws + o); o += (size_t)CC * CC * 2;
  __hip_bfloat16* xmB = (__hip_bfloat16*)(ws + o); o += (size_t)MP * CC * 2;
  __hip_bfloat16* vB  = (__hip_bfloat16*)(ws + o); o += (size_t)MP * CC * 2;
  __hip_bfloat16* rB  = (__hip_bfloat16*)(ws + o); o += (size_t)MP * CC * 2;

  float* kraw = (float*)d_out;
  __hip_bfloat16* rwkvB = xmB;

  cast_weights<<<CC * CC / 1024, 256, 0, stream>>>(Wk, Wv, Wr, Wo, W3, WoB);
  build_xm<<<MP, 256, 0, stream>>>(x, xx, tmix, xmB);
  gemm256<1><<<dim3(N3 / 256, MP / 256), 512, 0, stream>>>(
      (const short*)xmB, (const short*)W3, kraw, vB, rB);
  scan_fuse2<<<dim3(CC / 128, BB), 1024, 0, stream>>>(kraw, vB, rB, aa, bb, mm,
                                                      tdec, tfir, rwkvB);
  gemm256<0><<<dim3(CC / 256, MP / 256), 512, 0, stream>>>(
      (const short*)rwkvB, (const short*)WoB, (float*)d_out, nullptr, nullptr);
}

// Round 7
// 701.225 us; speedup vs baseline: 1.1224x; 1.0946x over previous
//
#include <hip/hip_runtime.h>
#include <hip/hip_bf16.h>
#include <math.h>
#include <float.h>

#define BB 16
#define TT 1023
#define CC 2048
#define M_ROWS (BB * TT)   // 16368
#define MP 16384           // padded rows
#define N3 (3 * CC)        // 6144
#define NCH 16             // scan chunks
#define CHL 64             // chunk length

typedef __attribute__((ext_vector_type(8))) short bfrag;   // 8 bf16 (4 VGPRs)
typedef __attribute__((ext_vector_type(4))) float f32x4;   // MFMA C/D frag
typedef __attribute__((ext_vector_type(4))) short short4v;

__device__ __forceinline__ void async16(const void* g, void* l) {
  __builtin_amdgcn_global_load_lds((const __attribute__((address_space(1))) void*)g,
                                   (__attribute__((address_space(3))) void*)l, 16, 0, 0);
}

__device__ __forceinline__ short bfb(float f) {
  __hip_bfloat16 h = __float2bfloat16(f);
  return *reinterpret_cast<short*>(&h);
}

// ---------------- weight fp32 -> bf16 (float4 vectorized) ----------------
__global__ void cast_weights(const float* __restrict__ Wk, const float* __restrict__ Wv,
                             const float* __restrict__ Wr, const float* __restrict__ Wo,
                             __hip_bfloat16* __restrict__ W3, __hip_bfloat16* __restrict__ WoB) {
  size_t i4 = (size_t)blockIdx.x * 256 + threadIdx.x;      // grid covers CC*CC/4
  size_t i = i4 * 4;
  float4 a = *(const float4*)(Wk + i);
  float4 b = *(const float4*)(Wv + i);
  float4 c = *(const float4*)(Wr + i);
  float4 d = *(const float4*)(Wo + i);
  *(short4v*)((short*)W3 + i)              = short4v{bfb(a.x), bfb(a.y), bfb(a.z), bfb(a.w)};
  *(short4v*)((short*)W3 + i + CC * CC)    = short4v{bfb(b.x), bfb(b.y), bfb(b.z), bfb(b.w)};
  *(short4v*)((short*)W3 + i + 2 * CC * CC) = short4v{bfb(c.x), bfb(c.y), bfb(c.z), bfb(c.w)};
  *(short4v*)((short*)WoB + i)             = short4v{bfb(d.x), bfb(d.y), bfb(d.z), bfb(d.w)};
}

// ---------------- xm = x*tm + shift(x)*(1-tm), bf16, padded to MP rows ----------------
__global__ void build_xm(const float* __restrict__ x, const float* __restrict__ xx,
                         const float* __restrict__ tmix, __hip_bfloat16* __restrict__ xm) {
  int m = blockIdx.x;
  short* orow = (short*)xm + (size_t)m * CC;
  if (m >= M_ROWS) {
    for (int c = threadIdx.x; c < CC / 4; c += 256)
      ((short4v*)orow)[c] = short4v{0, 0, 0, 0};
    return;
  }
  int b = m / TT, t = m - b * TT;
  const float* xrow = x + (size_t)m * CC;
  const float* xprev = (t == 0) ? (xx + (size_t)b * CC) : (xrow - CC);
  for (int c = threadIdx.x; c < CC / 4; c += 256) {
    float4 xv = ((const float4*)xrow)[c];
    float4 pv = ((const float4*)xprev)[c];
    float4 tm = ((const float4*)tmix)[c];
    ((short4v*)orow)[c] = short4v{
        bfb(xv.x * tm.x + pv.x * (1.0f - tm.x)),
        bfb(xv.y * tm.y + pv.y * (1.0f - tm.y)),
        bfb(xv.z * tm.z + pv.z * (1.0f - tm.z)),
        bfb(xv.w * tm.w + pv.w * (1.0f - tm.w))};
  }
}

// ---------------- 256x256-tile 8-phase bf16 MFMA GEMM (T1+T2+T3+T4+T5) ----------------
// C[m,n] = sum_k A[m,k]*B[n,k].  8 waves (2M x 4N), BK=64 as 2 K-halves.
// LDS: 2 buf x 2 khalf x {A,B} regions of 256x32 bf16 (16 KB each) = 128 KB.
// Swizzle: 16B chunk at (row, slot) holds kgrp = slot ^ ((row>>1)&3).
// vmcnt cadence: VM(2) at phases 4 & 8 -> airtight ledger:
//   after ph4-VM(2): outstanding={s3,s4}; after ph8-VM(2): outstanding={s7,s8};
//   every staged region provably lands before the barrier preceding its reads.
template <int MODE>
__global__ __launch_bounds__(512, 2)
void gemm256(const short* __restrict__ A, const short* __restrict__ Bw,
             float* __restrict__ outF, __hip_bfloat16* __restrict__ outV,
             __hip_bfloat16* __restrict__ outR) {
  __shared__ short lds[65536];   // 128 KiB

  const int lane = threadIdx.x & 63, wid = threadIdx.x >> 6;
  const int wr = wid >> 2, wc = wid & 3;

  // XCD-aware swizzle (grids are multiples of 8)
  const int nx = gridDim.x;
  const int nwg = nx * gridDim.y;
  const int bid = blockIdx.y * nx + blockIdx.x;
  const int q = nwg >> 3;
  const int swz = (bid & 7) * q + (bid >> 3);
  const int mBase = (swz / nx) * 256;
  const int nBase = (swz % nx) * 256;

  // staging: wave wid covers rows [wid*32, wid*32+32) of the 256-row region
  const int srow = lane >> 2;                                  // 0..15
  const int scol = (((lane & 3) ^ ((lane >> 3) & 3)) * 8);     // inverse-swizzled k-group
  const int stgOff = wid * 1024 + lane * 8;                    // shorts
  const short* aSrcBase = A  + (size_t)(mBase + wid * 32 + srow) * CC + scol;
  const short* bSrcBase = Bw + (size_t)(nBase + wid * 32 + srow) * CC + scol;

  // ds_read: frag lane -> (row = R0 + (l&15), kgrp = l>>4), swizzled slot
  const int ldOff = (lane & 15) * 32 + (((lane >> 4) ^ ((lane >> 1) & 3)) * 8);  // shorts

  // hoisted per-buffer LDS read bases; all further addressing is imm offsets
  const short* pA0 = lds + wr * 128 * 32 + ldOff;            // buf0 A
  const short* pA1 = pA0 + 32768;                            // buf1 A
  const short* pB0 = lds + 16384 + wc * 64 * 32 + ldOff;     // buf0 B
  const short* pB1 = pB0 + 32768;                            // buf1 B

  f32x4 acc[2][4][4] = {};
  bfrag bq[4];

#define RGNA(buf, kh) ((buf) * 32768 + (kh) * 8192)
#define RGNB(buf, kh) (16384 + (buf) * 32768 + (kh) * 8192)

#define STG_A(buf, kh, tk) do { \
    const short* _s = aSrcBase + ((tk) * 64 + (kh) * 32); \
    short* _d = lds + RGNA(buf, kh) + stgOff; \
    async16(_s, _d); async16(_s + (size_t)16 * CC, _d + 512); } while (0)

#define STG_B(buf, kh, tk) do { \
    const short* _s = bSrcBase + ((tk) * 64 + (kh) * 32); \
    short* _d = lds + RGNB(buf, kh) + stgOff; \
    async16(_s, _d); async16(_s + (size_t)16 * CC, _d + 512); } while (0)

#define VMN(n) asm volatile("s_waitcnt vmcnt(" #n ")" ::: "memory")

// pA/pB are hoisted base pointers; kh/mh/f/n fold into ds_read offset imm.
#define PH(pA, pB, kh, mh, STAGE, WAIT) do { \
    bfrag aq[4]; \
    if ((mh) == 0) { \
      _Pragma("unroll") \
      for (int n = 0; n < 4; ++n) \
        bq[n] = *(const bfrag*)(pB + (kh) * 8192 + n * 16 * 32); \
    } \
    _Pragma("unroll") \
    for (int f = 0; f < 4; ++f) \
      aq[f] = *(const bfrag*)(pA + (kh) * 8192 + ((mh) * 64 + f * 16) * 32); \
    STAGE; \
    __builtin_amdgcn_s_barrier(); \
    __builtin_amdgcn_s_setprio(1); \
    _Pragma("unroll") \
    for (int f = 0; f < 4; ++f) \
      _Pragma("unroll") \
      for (int n = 0; n < 4; ++n) \
        acc[mh][f][n] = __builtin_amdgcn_mfma_f32_16x16x32_bf16(aq[f], bq[n], acc[mh][f][n], 0, 0, 0); \
    __builtin_amdgcn_s_setprio(0); \
    WAIT; \
    __builtin_amdgcn_s_barrier(); } while (0)

  // prologue: tile0 -> buf0 (both K-halves), tile1 K0 -> buf1 (6 units).
  // VM(2): 4 oldest (= buf0 both halves) landed -> covers iter-0 ph1..4 reads.
  STG_A(0, 0, 0); STG_B(0, 0, 0);
  STG_A(0, 1, 0); STG_B(0, 1, 0);
  STG_A(1, 0, 1); STG_B(1, 0, 1);
  VMN(2);
  __builtin_amdgcn_s_barrier();

  // steady state: 8 phases consume 2 K-tiles (buf0 then buf1), stage 8 units
  // s1..s8 = A11,B11,A00,B00,A01,B01,A10,B10 (next tiles).
  // ph4-VM(2): lands {A10,B10 prev, s1,s2} -> covers ph5..8 reads.
  // ph8-VM(2): lands {s3..s6} -> covers next iter ph1..4 reads.
  for (int ti = 0; ti < 30; ti += 2) {
    PH(pA0, pB0, 0, 0, STG_A(1, 1, ti + 1), );
    PH(pA0, pB0, 0, 1, STG_B(1, 1, ti + 1), );
    PH(pA0, pB0, 1, 0, STG_A(0, 0, ti + 2), );
    PH(pA0, pB0, 1, 1, STG_B(0, 0, ti + 2), VMN(2));
    PH(pA1, pB1, 0, 0, STG_A(0, 1, ti + 2), );
    PH(pA1, pB1, 0, 1, STG_B(0, 1, ti + 2), );
    PH(pA1, pB1, 1, 0, STG_A(1, 0, ti + 3), );
    PH(pA1, pB1, 1, 1, STG_B(1, 0, ti + 3), VMN(2));
  }
  // epilogue: tile 30 in buf0 (staged), tile 31 in buf1 (K0 staged; K1 here).
  PH(pA0, pB0, 0, 0, STG_A(1, 1, 31), );
  PH(pA0, pB0, 0, 1, STG_B(1, 1, 31), );
  PH(pA0, pB0, 1, 0, , );
  PH(pA0, pB0, 1, 1, , VMN(2));   // lands {A10,B10} (buf1.K0) -> ph5-6 reads
  PH(pA1, pB1, 0, 0, , );
  PH(pA1, pB1, 0, 1, , VMN(0));   // lands epi {s1,s2} (buf1.K1) -> ph7-8 reads
  PH(pA1, pB1, 1, 0, , );
  PH(pA1, pB1, 1, 1, , );

#undef PH
#undef VMN
#undef STG_A
#undef STG_B
#undef RGNA
#undef RGNB

  // C-write: col = lane&15, row = (lane>>4)*4 + rr (verified layout)
#pragma unroll
  for (int mh = 0; mh < 2; ++mh)
#pragma unroll
    for (int f = 0; f < 4; ++f) {
      const int row0 = mBase + wr * 128 + mh * 64 + f * 16 + (lane >> 4) * 4;
      const int col0 = nBase + wc * 64 + (lane & 15);
#pragma unroll
      for (int n = 0; n < 4; ++n) {
        const int col = col0 + n * 16;
#pragma unroll
        for (int rr = 0; rr < 4; ++rr) {
          const int row = row0 + rr;
          if (row < M_ROWS) {
            float val = acc[mh][f][n][rr];
            if constexpr (MODE == 0) {
              outF[(size_t)row * CC + col] = val;
            } else {
              if (col < CC)          outF[(size_t)row * CC + col] = val;
              else if (col < 2 * CC) outV[(size_t)row * CC + (col - CC)] = __float2bfloat16(val);
              else                   outR[(size_t)row * CC + (col - 2 * CC)] = __float2bfloat16(val);
            }
          }
        }
      }
    }
}

// ---------------- chunked parallel scan + sigmoid(r)*wkv/wk ----------------
// Renorm (mm_new) removed: wkv/wk is exactly invariant to it; state init is
// bb*exp(mm), aa*exp(mm). exp(kraw) is safely bounded in fp32 for this data.
__global__ __launch_bounds__(1024)
void scan_fuse2(const float* __restrict__ kraw, const __hip_bfloat16* __restrict__ v,
                const __hip_bfloat16* __restrict__ r, const float* __restrict__ aa,
                const float* __restrict__ bb, const float* __restrict__ mm,
                const float* __restrict__ tdec, const float* __restrict__ tfir,
                __hip_bfloat16* __restrict__ rwkv) {
  __shared__ float sBk[NCH][64], sBkv[NCH][64], sSk[NCH][64], sSkv[NCH][64];

  const int lane = threadIdx.x & 63, wid = threadIdx.x >> 6;
  const int c = blockIdx.x * 64 + lane;
  const int b = blockIdx.y;
  const int i = b * CC + c;

  const float dexp = expf(tdec[c]);
  const float d    = expf(-dexp);
  const float ef   = expf(tfir[c]);

  const int t0 = wid * CHL;
  const int t1 = (t0 + CHL < TT) ? t0 + CHL : TT;
  const size_t base = (size_t)b * TT * CC + c;

  if (wid < NCH - 1) {
    float Bk = 0.0f, Bkv = 0.0f;
    size_t off = base + (size_t)t0 * CC;
#pragma unroll 4
    for (int t = t0; t < t1; ++t, off += CC) {
      float kk = expf(kraw[off]);
      float kv = kk * __bfloat162float(v[off]);
      Bk = d * Bk + kk;
      Bkv = d * Bkv + kv;
    }
    sBk[wid][lane] = Bk;
    sBkv[wid][lane] = Bkv;
  }
  __syncthreads();

  if (wid == 0) {
    const float d64 = expf(-dexp * (float)CHL);
    const float sc = expf(mm[i]);
    float S = bb[i] * sc, Sv = aa[i] * sc;
#pragma unroll
    for (int j = 0; j < NCH; ++j) {
      sSk[j][lane] = S;
      sSkv[j][lane] = Sv;
      if (j < NCH - 1) {
        S = d64 * S + sBk[j][lane];
        Sv = d64 * Sv + sBkv[j][lane];
      }
    }
  }
  __syncthreads();

  float S = sSk[wid][lane], Sv = sSkv[wid][lane];
  size_t off = base + (size_t)t0 * CC;
#pragma unroll 4
  for (int t = t0; t < t1; ++t, off += CC) {
    float kk = expf(kraw[off]);
    float vv = __bfloat162float(v[off]);
    float rv = __bfloat162float(r[off]);
    float kv = kk * vv;
    float wk = ef * kk + S;
    float wkv = ef * kv + Sv;
    S = d * S + kk;
    Sv = d * Sv + kv;
    float ratio = wkv / wk;
    if (isnan(ratio)) ratio = 0.0f;
    else if (isinf(ratio)) ratio = ratio > 0.0f ? FLT_MAX : -FLT_MAX;
    float sig = 1.0f / (1.0f + expf(-rv));
    rwkv[off] = __float2bfloat16(sig * ratio);
  }
}

extern "C" void kernel_launch(void* const* d_in, const int* in_sizes, int n_in,
                              void* d_out, int out_size, void* d_ws, size_t ws_size,
                              hipStream_t stream) {
  const float* x    = (const float*)d_in[0];
  const float* tdec = (const float*)d_in[1];
  const float* tfir = (const float*)d_in[2];
  const float* tmix = (const float*)d_in[3];
  const float* Wk   = (const float*)d_in[4];
  const float* Wv   = (const float*)d_in[5];
  const float* Wr   = (const float*)d_in[6];
  const float* Wo   = (const float*)d_in[7];
  const float* xx   = (const float*)d_in[8];
  const float* aa   = (const float*)d_in[9];
  const float* bb   = (const float*)d_in[10];
  const float* mm   = (const float*)d_in[11];

  char* ws = (char*)d_ws;
  size_t o = 0;
  __hip_bfloat16* W3  = (__hip_bfloat16*)(ws + o); o += (size_t)N3 * CC * 2;
  __hip_bfloat16* WoB = (__hip_bfloat16*)(ws + o); o += (size_t)CC * CC * 2;
  __hip_bfloat16* xmB = (__hip_bfloat16*)(ws + o); o += (size_t)MP * CC * 2;
  __hip_bfloat16* vB  = (__hip_bfloat16*)(ws + o); o += (size_t)MP * CC * 2;
  __hip_bfloat16* rB  = (__hip_bfloat16*)(ws + o); o += (size_t)MP * CC * 2;

  float* kraw = (float*)d_out;
  __hip_bfloat16* rwkvB = xmB;

  cast_weights<<<CC * CC / 1024, 256, 0, stream>>>(Wk, Wv, Wr, Wo, W3, WoB);
  build_xm<<<MP, 256, 0, stream>>>(x, xx, tmix, xmB);
  gemm256<1><<<dim3(N3 / 256, MP / 256), 512, 0, stream>>>(
      (const short*)xmB, (const short*)W3, kraw, vB, rB);
  scan_fuse2<<<dim3(CC / 64, BB), 1024, 0, stream>>>(kraw, vB, rB, aa, bb, mm,
                                                     tdec, tfir, rwkvB);
  gemm256<0><<<dim3(CC / 256, MP / 256), 512, 0, stream>>>(
      (const short*)rwkvB, (const short*)WoB, (float*)d_out, nullptr, nullptr);
}